// Round 2
// baseline (109.832 us; speedup 1.0000x reference)
//
#include <hip/hip_runtime.h>

#define B_   4
#define Q_   256
#define C_   1024
#define H_   128
#define NEG  0.01f

// ---------------------------------------------------------------------------
// Kernel 1: k-major projections.
//   hc_t[b,k,c] = sum_h context[b,c,h]*Ww[k,H+h] + bw[k]   (256 blocks)
//   hq_t[b,k,q] = sum_h query[b,q,h]  *Ww[k,h]             (64 blocks)
// Block = 256 threads (4 waves). Stage 64 input rows in LDS (padded stride
// 33 float4 -> conflict-free). Thread = (lane c 0..63, wave kg 0..3), 8 k per
// thread. Ww loads are wave-uniform (scalarizable); output stores are
// 256 B-contiguous per wave (coalesced).
// ---------------------------------------------------------------------------
__global__ __launch_bounds__(256) void proj_kernel(
    const float* __restrict__ query, const float* __restrict__ context,
    const float* __restrict__ Ww, const float* __restrict__ bw,
    float* __restrict__ hq_t, float* __restrict__ hc_t)
{
    const int x = blockIdx.x;
    const int t = threadIdx.x;
    const bool is_c = (x < 256);
    int b, tile, ks, R, w_off;
    const float* __restrict__ in;
    float* __restrict__ out;
    if (is_c) { b = x >> 6; tile = (x >> 2) & 15; ks = x & 3; R = C_; w_off = 32; in = context; out = hc_t; }
    else { const int y = x - 256; b = y >> 4; tile = (y >> 2) & 3; ks = y & 3; R = Q_; w_off = 0; in = query; out = hq_t; }
    const int c0 = tile * 64;

    __shared__ float4 lds[64 * 33];   // 64 rows x 32 float4, stride 33 (pad)

    const float4* __restrict__ in4 = reinterpret_cast<const float4*>(in);
    const float4* __restrict__ Ww4 = reinterpret_cast<const float4*>(Ww);

    #pragma unroll
    for (int i = 0; i < 8; ++i) {
        const int idx = t + i * 256;            // 0..2047 float4s, coalesced
        const int row = idx >> 5, col = idx & 31;
        lds[row * 33 + col] = in4[(b * R + c0 + row) * 32 + col];
    }
    __syncthreads();

    const int c  = t & 63;                      // lane -> output column
    const int kg = t >> 6;                      // wave -> k-group
    const int kb = ks * 32 + kg * 8;            // first of 8 k for this thread

    float acc[8] = {0.f,0.f,0.f,0.f,0.f,0.f,0.f,0.f};
    #pragma unroll 8
    for (int h4 = 0; h4 < 32; ++h4) {
        const float4 cv = lds[c * 33 + h4];
        #pragma unroll
        for (int j = 0; j < 8; ++j) {
            const float4 w = Ww4[(kb + j) * 64 + w_off + h4];   // wave-uniform
            acc[j] += cv.x * w.x + cv.y * w.y + cv.z * w.z + cv.w * w.w;
        }
    }
    #pragma unroll
    for (int j = 0; j < 8; ++j) {
        const float bias = is_c ? bw[kb + j] : 0.f;
        out[(b * H_ + kb + j) * R + c0 + c] = acc[j] + bias;    // coalesced
    }
}

// ---------------------------------------------------------------------------
// Kernel 2: per block = (b, 4 consecutive q). 512 threads (8 waves).
// Phase 1: thread owns c in {2t, 2t+1}; loop over k: wave-uniform hq_t/Ws
//          loads, coalesced float2 hc_t load (k-major layout).
// Phase 2: softmax over c per q (wave shuffle butterflies + LDS combine).
// Phase 3: attn_output via 16-way c-split partial sums + LDS reduction.
// bs omitted: softmax is shift-invariant, both outputs are post-softmax.
// ---------------------------------------------------------------------------
__global__ __launch_bounds__(512) void attn_kernel(
    const float* __restrict__ hq_t, const float* __restrict__ hc_t,
    const float* __restrict__ Ws, const float* __restrict__ context,
    float* __restrict__ outA, float* __restrict__ outP)
{
    const int b  = blockIdx.x >> 6;          // 4 b
    const int q0 = (blockIdx.x & 63) * 4;    // 64 q-groups per b
    const int t  = threadIdx.x;
    const int wv = t >> 6;                   // wave id 0..7

    __shared__ float4 attn4_s[C_];           // 16 KiB: attn packed {q0..q3} per c
    __shared__ float  red[16 * 4 * H_];      // 32 KiB: phase-3 partials
    __shared__ float  wred[8][4];
    __shared__ float  wsum[8][4];

    const float4* __restrict__ hq4  = reinterpret_cast<const float4*>(hq_t);
    const float2* __restrict__ hc2  = reinterpret_cast<const float2*>(hc_t);
    const float4* __restrict__ ctx4 = reinterpret_cast<const float4*>(context);

    // ---- phase 1: scores; thread owns c = 2t, 2t+1
    float s[4][2] = {{0.f,0.f},{0.f,0.f},{0.f,0.f},{0.f,0.f}};
    const int q04 = q0 >> 2;
    #pragma unroll 4
    for (int k = 0; k < H_; ++k) {
        const float  wsk = Ws[k];                                // uniform
        const float4 hqv = hq4[(b * H_ + k) * (Q_ / 4) + q04];   // uniform, 4 q
        const float2 hv  = hc2[(b * H_ + k) * (C_ / 2) + t];     // coalesced
        float x, y;
        x = hqv.x + hv.x; y = hqv.x + hv.y;
        x = fmaxf(x, NEG * x); y = fmaxf(y, NEG * y);
        s[0][0] += wsk * x; s[0][1] += wsk * y;
        x = hqv.y + hv.x; y = hqv.y + hv.y;
        x = fmaxf(x, NEG * x); y = fmaxf(y, NEG * y);
        s[1][0] += wsk * x; s[1][1] += wsk * y;
        x = hqv.z + hv.x; y = hqv.z + hv.y;
        x = fmaxf(x, NEG * x); y = fmaxf(y, NEG * y);
        s[2][0] += wsk * x; s[2][1] += wsk * y;
        x = hqv.w + hv.x; y = hqv.w + hv.y;
        x = fmaxf(x, NEG * x); y = fmaxf(y, NEG * y);
        s[3][0] += wsk * x; s[3][1] += wsk * y;
    }

    // ---- phase 2: softmax over the 1024 c per q row
    float m[4];
    #pragma unroll
    for (int q = 0; q < 4; ++q) {
        float v = fmaxf(s[q][0], s[q][1]);
        #pragma unroll
        for (int off = 32; off >= 1; off >>= 1)
            v = fmaxf(v, __shfl_xor(v, off, 64));
        m[q] = v;
    }
    if ((t & 63) == 0) {
        #pragma unroll
        for (int q = 0; q < 4; ++q) wred[wv][q] = m[q];
    }
    __syncthreads();
    #pragma unroll
    for (int q = 0; q < 4; ++q) {
        float v = wred[0][q];
        #pragma unroll
        for (int i = 1; i < 8; ++i) v = fmaxf(v, wred[i][q]);
        m[q] = v;
    }
    float e[4][2], p[4];
    #pragma unroll
    for (int q = 0; q < 4; ++q) {
        e[q][0] = __expf(s[q][0] - m[q]);
        e[q][1] = __expf(s[q][1] - m[q]);
        float v = e[q][0] + e[q][1];
        #pragma unroll
        for (int off = 32; off >= 1; off >>= 1)
            v += __shfl_xor(v, off, 64);
        p[q] = v;
    }
    if ((t & 63) == 0) {
        #pragma unroll
        for (int q = 0; q < 4; ++q) wsum[wv][q] = p[q];
    }
    __syncthreads();
    float rS[4];
    #pragma unroll
    for (int q = 0; q < 4; ++q) {
        float S = wsum[0][q];
        #pragma unroll
        for (int i = 1; i < 8; ++i) S += wsum[i][q];
        rS[q] = 1.0f / S;
    }
    float a0[4], a1[4];
    #pragma unroll
    for (int q = 0; q < 4; ++q) {
        a0[q] = e[q][0] * rS[q];
        a1[q] = e[q][1] * rS[q];
    }
    attn4_s[2 * t]     = make_float4(a0[0], a0[1], a0[2], a0[3]);
    attn4_s[2 * t + 1] = make_float4(a1[0], a1[1], a1[2], a1[3]);
    float2* __restrict__ outP2 = reinterpret_cast<float2*>(outP);
    #pragma unroll
    for (int q = 0; q < 4; ++q)
        outP2[(b * Q_ + q0 + q) * (C_ / 2) + t] = make_float2(a0[q], a1[q]);
    __syncthreads();

    // ---- phase 3: attn_output[q][h] = sum_c attn[q][c]*context[b][c][h]
    const int hg   = t & 31;      // float4 h-chunk: h = hg*4..hg*4+3
    const int crep = t >> 5;      // 16 c-chunks of 64
    float4 acc[4] = {{0,0,0,0},{0,0,0,0},{0,0,0,0},{0,0,0,0}};
    const int cb = crep * 64;
    #pragma unroll 4
    for (int cc = 0; cc < 64; ++cc) {
        const int c = cb + cc;
        const float4 a4 = attn4_s[c];
        const float4 xv = ctx4[(b * C_ + c) * (H_ / 4) + hg];
        acc[0].x += a4.x * xv.x; acc[0].y += a4.x * xv.y; acc[0].z += a4.x * xv.z; acc[0].w += a4.x * xv.w;
        acc[1].x += a4.y * xv.x; acc[1].y += a4.y * xv.y; acc[1].z += a4.y * xv.z; acc[1].w += a4.y * xv.w;
        acc[2].x += a4.z * xv.x; acc[2].y += a4.z * xv.y; acc[2].z += a4.z * xv.z; acc[2].w += a4.z * xv.w;
        acc[3].x += a4.w * xv.x; acc[3].y += a4.w * xv.y; acc[3].z += a4.w * xv.z; acc[3].w += a4.w * xv.w;
    }
    float4* red4 = reinterpret_cast<float4*>(red);
    #pragma unroll
    for (int q = 0; q < 4; ++q)
        red4[(crep * 4 + q) * 32 + hg] = acc[q];
    __syncthreads();
    {
        const int q = t >> 7, h = t & 127;
        float v = 0.f;
        #pragma unroll
        for (int cr = 0; cr < 16; ++cr)
            v += red[(cr * 4 + q) * H_ + h];
        outA[(b * Q_ + q0 + q) * H_ + h] = v;
    }
}

extern "C" void kernel_launch(void* const* d_in, const int* in_sizes, int n_in,
                              void* d_out, int out_size, void* d_ws, size_t ws_size,
                              hipStream_t stream) {
    const float* query   = (const float*)d_in[0];
    const float* context = (const float*)d_in[1];
    const float* Ww      = (const float*)d_in[2];
    const float* bw      = (const float*)d_in[3];
    const float* Ws      = (const float*)d_in[4];
    // d_in[5] (bs) intentionally unused: softmax is shift-invariant and both
    // outputs are post-softmax quantities.

    float* outA = (float*)d_out;                 // attn_output: B*Q*H
    float* outP = outA + B_ * Q_ * H_;           // attn:        B*Q*C

    float* hq_t = (float*)d_ws;                  // [b][k][q]: B*H*Q floats (512 KB)
    float* hc_t = hq_t + B_ * H_ * Q_;           // [b][k][c]: B*H*C floats (2 MB)

    hipLaunchKernelGGL(proj_kernel, dim3(320), dim3(256), 0, stream,
                       query, context, Ww, bw, hq_t, hc_t);
    hipLaunchKernelGGL(attn_kernel, dim3(256), dim3(512), 0, stream,
                       hq_t, hc_t, Ws, context, outA, outP);
}